// Round 20
// baseline (163.928 us; speedup 1.0000x reference)
//
#include <hip/hip_runtime.h>

#define N_NODES   50000
#define N_EDGES   800000
#define NODE_DIM  128
#define HIDDEN    256
#define LATENT    128
#define COND      5

#define NB        196                          // buckets: dst>>8 (256-node ranges)
#define P1_CHUNK  4096
#define P1_GRID   ((N_EDGES + P1_CHUNK - 1) / P1_CHUNK)  // 196

typedef unsigned int uint;
typedef unsigned short ushort;
typedef unsigned char uchar;

typedef __attribute__((ext_vector_type(8))) short bf16x8;
typedef __attribute__((ext_vector_type(4))) float f32x4;

static __device__ __forceinline__ ushort f32_to_bf16(float f) {
    union { float f; uint u; } v; v.f = f;
    uint r = v.u + 0x7FFF + ((v.u >> 16) & 1);   // RNE
    return (ushort)(r >> 16);
}
static __device__ __forceinline__ uint pack_bf16(float lo, float hi) {
    return (uint)f32_to_bf16(lo) | ((uint)f32_to_bf16(hi) << 16);
}

// ---------------- fp8 e4m3 helpers (HW cvt with software fallback) ----------------

#if __has_builtin(__builtin_amdgcn_cvt_pk_f32_fp8) && __has_builtin(__builtin_amdgcn_cvt_pk_fp8_f32)
#define HW_FP8 1
#endif

#ifndef HW_FP8
static __device__ __forceinline__ float dec1_fp8(uint b) {
    uint sgn = b & 0x80, mag = b & 0x7f;
    float v;
    if (mag >= 8) {
        union { uint u; float f; } t;
        t.u = (((mag >> 3) + 120) << 23) | ((mag & 7) << 20);
        v = t.f;
    } else {
        v = (float)mag * 0.001953125f;   // 2^-9
    }
    return sgn ? -v : v;
}
static __device__ __forceinline__ uchar enc1_fp8(float f) {
    float a = fabsf(f);
    uint s = (f < 0.f) ? 0x80u : 0u;
    if (!(a >= 0.015625f)) {
        int q = (int)(a * 512.f + 0.5f);
        if (q > 7) q = 7;
        return (uchar)(s | (uint)q);
    }
    if (a >= 448.f) return (uchar)(s | 0x7E);
    union { float f; uint u; } t; t.f = a;
    uint e = (t.u >> 23) - 120;
    uint m = (t.u >> 20) & 7;
    uint rem = t.u & 0xFFFFF;
    uint v = (e << 3) | m;
    if (rem > 0x80000 || (rem == 0x80000 && (v & 1))) v++;
    if (v > 0x7E) v = 0x7E;
    return (uchar)(s | v);
}
#endif

static __device__ __forceinline__ void dec4_add(uint u, float* acc) {
#ifdef HW_FP8
    auto lo = __builtin_amdgcn_cvt_pk_f32_fp8((int)u, false);
    auto hi = __builtin_amdgcn_cvt_pk_f32_fp8((int)u, true);
    acc[0] += lo[0]; acc[1] += lo[1]; acc[2] += hi[0]; acc[3] += hi[1];
#else
    acc[0] += dec1_fp8(u & 0xff);
    acc[1] += dec1_fp8((u >> 8) & 0xff);
    acc[2] += dec1_fp8((u >> 16) & 0xff);
    acc[3] += dec1_fp8(u >> 24);
#endif
}
static __device__ __forceinline__ void dec2_add(uint u, float* acc) {
#ifdef HW_FP8
    auto lo = __builtin_amdgcn_cvt_pk_f32_fp8((int)u, false);
    acc[0] += lo[0]; acc[1] += lo[1];
#else
    acc[0] += dec1_fp8(u & 0xff);
    acc[1] += dec1_fp8((u >> 8) & 0xff);
#endif
}
static __device__ __forceinline__ uint enc2_fp8(float a, float b) {
#ifdef HW_FP8
    return (uint)__builtin_amdgcn_cvt_pk_fp8_f32(a, b, 0, false) & 0xFFFFu;
#else
    return (uint)enc1_fp8(a) | ((uint)enc1_fp8(b) << 8);
#endif
}
static __device__ __forceinline__ uchar enc1(float v) {
#ifdef HW_FP8
    return (uchar)(__builtin_amdgcn_cvt_pk_fp8_f32(v, v, 0, false) & 0xff);
#else
    return enc1_fp8(v);
#endif
}

// ---------------- prep: nf -> fp8, W -> transposed bf16 (Wt[c][k]), zero scratch ----------------

#define NF4   (N_NODES * NODE_DIM / 4)            // 1,600,000
#define PREP1 (NF4 + NODE_DIM * HIDDEN)           // + 32768  (W1)
#define PREP2 (PREP1 + HIDDEN * HIDDEN)           // + 65536  (W2)
#define PREP3 (PREP2 + HIDDEN)                    // + 256    (pooled zero)
#define PREP4 (PREP3 + NB)                        // + 196    (bcount zero)
#define PREP5 (PREP4 + NB)                        // + 196    (bcursor2 zero)
#define PREP6 (PREP5 + 1)                         // + 1      (hcnt zero)

__global__ void prep_kernel(const float* __restrict__ nf,
                            const float* __restrict__ W1, const float* __restrict__ W2,
                            uchar* __restrict__ nf_fp8,
                            ushort* __restrict__ Wt1, ushort* __restrict__ Wt2,
                            float* __restrict__ pooled,
                            int* __restrict__ bcount, int* __restrict__ bcursor2,
                            int* __restrict__ hcnt) {
    int id = blockIdx.x * blockDim.x + threadIdx.x;
    if (id < NF4) {
        float4 v = reinterpret_cast<const float4*>(nf)[id];
        uint w = enc2_fp8(v.x, v.y) | (enc2_fp8(v.z, v.w) << 16);
        reinterpret_cast<uint*>(nf_fp8)[id] = w;
    } else if (id < PREP1) {                       // W1 [128,256] -> Wt1 [256][128]
        int i = id - NF4;
        int k = i >> 8, c = i & 255;
        Wt1[c * NODE_DIM + k] = f32_to_bf16(W1[i]);
    } else if (id < PREP2) {                       // W2 [256,256] -> Wt2 [256][256]
        int i = id - PREP1;
        int k = i >> 8, c = i & 255;
        Wt2[c * HIDDEN + k] = f32_to_bf16(W2[i]);
    } else if (id < PREP3) {
        pooled[id - PREP2] = 0.f;
    } else if (id < PREP4) {
        bcount[id - PREP3] = 0;
    } else if (id < PREP5) {
        bcursor2[id - PREP4] = 0;
    } else if (id < PREP6) {
        hcnt[0] = 0;
    }
}

// ---------------- CSR build: bucket count -> pair write -> per-bucket local CSR ----------------

__global__ __launch_bounds__(256) void bcount_kernel(const int* __restrict__ dst,
                                                     int* __restrict__ bcount) {
    __shared__ int cnt[NB];
    const int t = threadIdx.x;
    for (int i = t; i < NB; i += 256) cnt[i] = 0;
    __syncthreads();
    const int base = blockIdx.x * P1_CHUNK;
#pragma unroll
    for (int i = 0; i < 16; ++i) {
        int e = base + i * 256 + t;
        if (e < N_EDGES) atomicAdd(&cnt[dst[e] >> 8], 1);
    }
    __syncthreads();
    for (int i = t; i < NB; i += 256)
        if (cnt[i] > 0) atomicAdd(&bcount[i], cnt[i]);
}

__global__ __launch_bounds__(256) void bwrite_kernel(const int* __restrict__ src,
                                                     const int* __restrict__ dst,
                                                     const int* __restrict__ bcount,
                                                     int* __restrict__ bcursor2,
                                                     uint* __restrict__ pair_buf) {
    __shared__ int s[256];
    __shared__ int cnt[NB];
    __shared__ int gbase[NB];
    const int t = threadIdx.x;
    s[t] = (t < NB) ? bcount[t] : 0;
    __syncthreads();
    for (int off = 1; off < 256; off <<= 1) {
        int v = (t >= off) ? s[t - off] : 0;
        __syncthreads();
        s[t] += v;
        __syncthreads();
    }
    for (int i = t; i < NB; i += 256) cnt[i] = 0;
    __syncthreads();

    const int base = blockIdx.x * P1_CHUNK;
    uint pk[16];
    int  bk[16], lr[16];
    bool ok[16];
#pragma unroll
    for (int i = 0; i < 16; ++i) {
        int e = base + i * 256 + t;
        ok[i] = e < N_EDGES;
        if (ok[i]) {
            int sv = src[e], d = dst[e];
            pk[i] = (uint)sv | ((uint)d << 16);
            bk[i] = d >> 8;
        }
    }
#pragma unroll
    for (int i = 0; i < 16; ++i)
        if (ok[i]) lr[i] = atomicAdd(&cnt[bk[i]], 1);
    __syncthreads();
    if (t < NB) {
        int c = cnt[t];
        if (c > 0) gbase[t] = ((t > 0) ? s[t - 1] : 0) + atomicAdd(&bcursor2[t], c);
    }
    __syncthreads();
#pragma unroll
    for (int i = 0; i < 16; ++i)
        if (ok[i]) pair_buf[gbase[bk[i]] + lr[i]] = pk[i];
}

__global__ __launch_bounds__(256) void csrloc_kernel(const uint* __restrict__ pair_buf,
                                                     const int* __restrict__ bcount,
                                                     int* __restrict__ offsets,
                                                     ushort* __restrict__ csr) {
    __shared__ int s[256];
    __shared__ int lcnt[256];
    __shared__ int loff[256];
    __shared__ int lcur[256];
    const int t = threadIdx.x;
    const int b = blockIdx.x;
    s[t] = (t < NB) ? bcount[t] : 0;
    __syncthreads();
    for (int off = 1; off < 256; off <<= 1) {
        int v = (t >= off) ? s[t - off] : 0;
        __syncthreads();
        s[t] += v;
        __syncthreads();
    }
    const int e0 = (b > 0) ? s[b - 1] : 0;
    const int e1 = s[b];
    lcnt[t] = 0;
    lcur[t] = 0;
    __syncthreads();

    for (int j = e0 + t; j < e1; j += 256)
        atomicAdd(&lcnt[(pair_buf[j] >> 16) & 255], 1);
    __syncthreads();

    const int myc = lcnt[t];
    s[t] = myc;
    __syncthreads();
    for (int off = 1; off < 256; off <<= 1) {
        int v = (t >= off) ? s[t - off] : 0;
        __syncthreads();
        s[t] += v;
        __syncthreads();
    }
    const int lofft = s[t] - myc;   // exclusive
    loff[t] = lofft;
    const int node = (b << 8) + t;
    if (node < N_NODES) offsets[node] = e0 + lofft;
    if (b == 0 && t == 0) offsets[N_NODES] = N_EDGES;
    __syncthreads();

    for (int j = e0 + t; j < e1; j += 256) {
        uint p = pair_buf[j];
        int dl = (int)(p >> 16) & 255;
        int r = atomicAdd(&lcur[dl], 1);
        csr[e0 + loff[dl] + r] = (ushort)(p & 0xFFFFu);
    }
}

// ---------------- aggregation: wave per node, fp8 gather, bf16 out, 16-deep pipeline ----------------

template <int D>
__global__ __launch_bounds__(256) void agg_kernel(const uchar* __restrict__ x,
                                                  const int* __restrict__ offsets,
                                                  const ushort* __restrict__ csr,
                                                  ushort* __restrict__ out) {
    constexpr int BPL = D / 64;   // bytes per lane: 2 or 4
    int node = (blockIdx.x * blockDim.x + threadIdx.x) >> 6;
    int lane = threadIdx.x & 63;
    if (node >= N_NODES) return;
    int j0 = __builtin_amdgcn_readfirstlane(offsets[node]);
    int j1 = __builtin_amdgcn_readfirstlane(offsets[node + 1]);

    float acc[BPL];
#pragma unroll
    for (int i = 0; i < BPL; ++i) acc[i] = 0.f;

    const uchar* base = x + lane * BPL;
    const int il = lane & 15;

    int idxv = (j0 + il < j1) ? (int)csr[j0 + il] : 0;

    for (int jb = j0; jb < j1; jb += 16) {
        int idxn = (jb + 16 + il < j1) ? (int)csr[jb + 16 + il] : 0;
        int n = j1 - jb; n = (n > 16) ? 16 : n;
        uint u[16];
        if (n == 16) {
#pragma unroll
            for (int i = 0; i < 16; ++i) {
                int s = __shfl(idxv, i);
                if constexpr (BPL == 4)
                    u[i] = *reinterpret_cast<const uint*>(base + (size_t)s * D);
                else
                    u[i] = *reinterpret_cast<const ushort*>(base + (size_t)s * D);
            }
#pragma unroll
            for (int i = 0; i < 16; ++i) {
                if constexpr (BPL == 4) dec4_add(u[i], acc); else dec2_add(u[i], acc);
            }
        } else {
#pragma unroll
            for (int i = 0; i < 16; ++i) {
                if (i < n) {
                    int s = __shfl(idxv, i);
                    if constexpr (BPL == 4)
                        u[i] = *reinterpret_cast<const uint*>(base + (size_t)s * D);
                    else
                        u[i] = *reinterpret_cast<const ushort*>(base + (size_t)s * D);
                }
            }
#pragma unroll
            for (int i = 0; i < 16; ++i) {
                if (i < n) {
                    if constexpr (BPL == 4) dec4_add(u[i], acc); else dec2_add(u[i], acc);
                }
            }
        }
        idxv = idxn;
    }

    if constexpr (BPL == 4) {
        uint2 o;
        o.x = pack_bf16(acc[0], acc[1]);
        o.y = pack_bf16(acc[2], acc[3]);
        *reinterpret_cast<uint2*>(out + (size_t)node * D + lane * 4) = o;
    } else {
        *reinterpret_cast<uint*>(out + (size_t)node * D + lane * 2) = pack_bf16(acc[0], acc[1]);
    }
}

// ---------------- GEMM1 (K=128): W pinned in registers, A double-buffered, no LDS/barriers ----------------
// grid 512 persistent; colhalf = bid/256 (co-located mod 8). Block = 64 rows x 128 cols.
// W frags (4x4 = 64 VGPR) pinned with asm so the allocator CANNOT rematerialize them.

__global__ __launch_bounds__(256, 2) void gemm1_kernel(const ushort* __restrict__ A,
                                                       const ushort* __restrict__ Wt,
                                                       const float* __restrict__ bias,
                                                       uchar* __restrict__ Xout, int nblk) {
    constexpr int K  = NODE_DIM;                 // 128
    constexpr int NT = (N_NODES + 63) / 64;      // 782

    const int lane = threadIdx.x & 63;
    const int wv   = threadIdx.x >> 6;
    const int fr   = lane & 15;
    const int kgl  = lane >> 4;
    const int half    = nblk >> 1;               // 256 (mod 8 == 0 -> co-located)
    const int colhalf = blockIdx.x / half;
    const int stride  = half;

    const int rowsel = (wv & 1) * 32;
    const int colsel = wv >> 1;
    const int col0   = colhalf * 128 + colsel * 64;

    // W fragments in registers: ks 0..3, ct 0..3 — pinned (cannot be rematerialized)
    bf16x8 w[4][4];
#pragma unroll
    for (int ks = 0; ks < 4; ++ks)
#pragma unroll
        for (int ct = 0; ct < 4; ++ct)
            w[ks][ct] = *reinterpret_cast<const bf16x8*>(
                Wt + (size_t)(col0 + ct * 16 + fr) * K + ks * 32 + kgl * 8);
#pragma unroll
    for (int ks = 0; ks < 4; ++ks)
        asm volatile("" : "+v"(w[ks][0]), "+v"(w[ks][1]), "+v"(w[ks][2]), "+v"(w[ks][3]));

    float bcol[4];
#pragma unroll
    for (int ct = 0; ct < 4; ++ct) bcol[ct] = bias[col0 + ct * 16 + fr];
    const int mrow = kgl * 4;

#define LOADA1(dst, tl)                                                            \
    {                                                                              \
        const int rb_ = (tl) * 64 + rowsel;                                        \
        _Pragma("unroll")                                                          \
        for (int rt = 0; rt < 2; ++rt) {                                           \
            const ushort* ap_ = A + (size_t)(rb_ + rt * 16 + fr) * K + kgl * 8;    \
            _Pragma("unroll")                                                      \
            for (int ks = 0; ks < 4; ++ks)                                         \
                dst[rt][ks] = *reinterpret_cast<const bf16x8*>(ap_ + ks * 32);     \
        }                                                                          \
    }

    int tile = blockIdx.x % half;
    bf16x8 afA[2][4];
    if (tile < NT) LOADA1(afA, tile)

    while (tile < NT) {
        const int tn = tile + stride;
        bf16x8 afB[2][4];
        if (tn < NT) LOADA1(afB, tn)       // issue next-tile loads before compute

        f32x4 acc[2][4];
#pragma unroll
        for (int rt = 0; rt < 2; ++rt)
#pragma unroll
            for (int ct = 0; ct < 4; ++ct)
                acc[rt][ct] = (f32x4){0.f, 0.f, 0.f, 0.f};

#pragma unroll
        for (int ks = 0; ks < 4; ++ks)
#pragma unroll
            for (int rt = 0; rt < 2; ++rt)
#pragma unroll
                for (int ct = 0; ct < 4; ++ct)
                    acc[rt][ct] = __builtin_amdgcn_mfma_f32_16x16x32_bf16(afA[rt][ks], w[ks][ct], acc[rt][ct], 0, 0, 0);

        const int rowb = tile * 64 + rowsel;
#pragma unroll
        for (int rt = 0; rt < 2; ++rt) {
#pragma unroll
            for (int e = 0; e < 4; ++e) {
                int m = rowb + rt * 16 + mrow + e;
                if (m < N_NODES) {
#pragma unroll
                    for (int ct = 0; ct < 4; ++ct) {
                        float v = fmaxf(acc[rt][ct][e] + bcol[ct], 0.f);
                        Xout[(size_t)m * HIDDEN + col0 + ct * 16 + fr] = enc1(v);
                    }
                }
            }
        }
#pragma unroll
        for (int rt = 0; rt < 2; ++rt)
#pragma unroll
            for (int ks = 0; ks < 4; ++ks)
                afA[rt][ks] = afB[rt][ks];
        tile = tn;
    }
#undef LOADA1
}

// ---------------- GEMM2 (K=256): W pinned in registers, A double-buffered, fused pool+head ----------------
// grid 512 persistent; colq = bid/128 (co-located mod 8). Block = 32 rows x 64 cols.
// W frags (8x2 = 64 VGPR) pinned.

__global__ __launch_bounds__(256, 2) void gemm2_kernel(const ushort* __restrict__ A,
                                                       const ushort* __restrict__ Wt,
                                                       const float* __restrict__ bias,
                                                       float* __restrict__ pooled, int nblk,
                                                       const float* __restrict__ cond,
                                                       const float* __restrict__ Wfc,
                                                       const float* __restrict__ bfc,
                                                       const float* __restrict__ Wmean,
                                                       const float* __restrict__ bmean,
                                                       const float* __restrict__ Wlogvar,
                                                       const float* __restrict__ blogvar,
                                                       float* __restrict__ outv,
                                                       int* __restrict__ hcnt) {
    constexpr int K  = HIDDEN;                   // 256
    constexpr int NT = (N_NODES + 31) / 32;      // 1563
    __shared__ float hv[HIDDEN + COND];
    __shared__ float hh[LATENT];
    __shared__ int lastflag;

    const int t    = threadIdx.x;
    const int lane = t & 63;
    const int wv   = t >> 6;
    const int fr   = lane & 15;
    const int kgl  = lane >> 4;
    const int q      = nblk >> 2;                // 128 (mod 8 == 0 -> co-located)
    const int colq   = blockIdx.x / q;
    const int stride = q;

    const int rowhalf = wv & 1;
    const int colh32  = wv >> 1;
    const int col0    = colq * 64 + colh32 * 32;

    // W fragments in registers: ks 0..7, ct 0..1 — pinned
    bf16x8 w[8][2];
#pragma unroll
    for (int ks = 0; ks < 8; ++ks)
#pragma unroll
        for (int ct = 0; ct < 2; ++ct)
            w[ks][ct] = *reinterpret_cast<const bf16x8*>(
                Wt + (size_t)(col0 + ct * 16 + fr) * K + ks * 32 + kgl * 8);
#pragma unroll
    for (int ks = 0; ks < 8; ++ks)
        asm volatile("" : "+v"(w[ks][0]), "+v"(w[ks][1]));

    float bcol[2];
    bcol[0] = bias[col0 + fr];
    bcol[1] = bias[col0 + 16 + fr];
    const int mrow = kgl * 4;

    float cs[2] = {0.f, 0.f};

#define LOADA2(dst, tl)                                                            \
    {                                                                              \
        const ushort* ap_ = A + (size_t)((tl) * 32 + rowhalf * 16 + fr) * K + kgl * 8; \
        _Pragma("unroll")                                                          \
        for (int ks = 0; ks < 8; ++ks)                                             \
            dst[ks] = *reinterpret_cast<const bf16x8*>(ap_ + ks * 32);             \
    }

    int tile = blockIdx.x % q;
    bf16x8 afA[8];
    if (tile < NT) LOADA2(afA, tile)

    while (tile < NT) {
        const int tn = tile + stride;
        bf16x8 afB[8];
        if (tn < NT) LOADA2(afB, tn)        // issue next-tile loads before compute

        f32x4 acc[2];
        acc[0] = (f32x4){0.f, 0.f, 0.f, 0.f};
        acc[1] = (f32x4){0.f, 0.f, 0.f, 0.f};
#pragma unroll
        for (int ks = 0; ks < 8; ++ks) {
            acc[0] = __builtin_amdgcn_mfma_f32_16x16x32_bf16(afA[ks], w[ks][0], acc[0], 0, 0, 0);
            acc[1] = __builtin_amdgcn_mfma_f32_16x16x32_bf16(afA[ks], w[ks][1], acc[1], 0, 0, 0);
        }

        const int rowb = tile * 32 + rowhalf * 16;
#pragma unroll
        for (int e = 0; e < 4; ++e) {
            int m = rowb + mrow + e;
            if (m < N_NODES) {
                cs[0] += fmaxf(acc[0][e] + bcol[0], 0.f);
                cs[1] += fmaxf(acc[1][e] + bcol[1], 0.f);
            }
        }
#pragma unroll
        for (int ks = 0; ks < 8; ++ks) afA[ks] = afB[ks];
        tile = tn;
    }
#undef LOADA2

#pragma unroll
    for (int ct = 0; ct < 2; ++ct) {
        cs[ct] += __shfl_xor(cs[ct], 16);
        cs[ct] += __shfl_xor(cs[ct], 32);
    }
    if (lane < 16) {
#pragma unroll
        for (int ct = 0; ct < 2; ++ct)
            atomicAdd(&pooled[col0 + ct * 16 + lane], cs[ct]);
    }

    // ---- fused head: last block runs the MLP ----
    asm volatile("s_waitcnt vmcnt(0)" ::: "memory");
    __syncthreads();
    if (t == 0) lastflag = (atomicAdd(hcnt, 1) == nblk - 1) ? 1 : 0;
    __syncthreads();
    if (lastflag) {
        if (t < HIDDEN) hv[t] = atomicAdd(&pooled[t], 0.0f) * (1.0f / N_NODES);
        if (t < COND) hv[HIDDEN + t] = cond[t];
        __syncthreads();
        if (t < LATENT) {
            float s = bfc[t];
            for (int k = 0; k < HIDDEN + COND; ++k) s += hv[k] * Wfc[k * LATENT + t];
            hh[t] = fmaxf(s, 0.f);
        }
        __syncthreads();
        if (t < LATENT) {
            float s = bmean[t];
            for (int k = 0; k < LATENT; ++k) s += hh[k] * Wmean[k * LATENT + t];
            outv[t] = s;
        } else if (t < 2 * LATENT) {
            int j = t - LATENT;
            float s = blogvar[j];
            for (int k = 0; k < LATENT; ++k) s += hh[k] * Wlogvar[k * LATENT + j];
            outv[LATENT + j] = s;
        }
    }
}

// ---------------- launch ----------------

extern "C" void kernel_launch(void* const* d_in, const int* in_sizes, int n_in,
                              void* d_out, int out_size, void* d_ws, size_t ws_size,
                              hipStream_t stream) {
    const float* node_features = (const float*)d_in[0];
    const float* conditions    = (const float*)d_in[1];
    const int*   src           = (const int*)d_in[2];
    const int*   dst           = (const int*)d_in[3];
    const float* W1  = (const float*)d_in[4];
    const float* b1  = (const float*)d_in[5];
    const float* W2  = (const float*)d_in[6];
    const float* b2  = (const float*)d_in[7];
    const float* Wfc = (const float*)d_in[8];
    const float* bfc = (const float*)d_in[9];
    const float* Wmean   = (const float*)d_in[10];
    const float* bmean   = (const float*)d_in[11];
    const float* Wlogvar = (const float*)d_in[12];
    const float* blogvar = (const float*)d_in[13];
    float* out = (float*)d_out;

    size_t o = 0;
    auto alloc = [&](size_t bytes) {
        void* p = (char*)d_ws + o;
        o += (bytes + 255) & ~(size_t)255;
        return p;
    };
    int* offsets   = (int*)alloc((size_t)(N_NODES + 1) * 4);
    int* bcount    = (int*)alloc((size_t)NB * 4);
    int* bcursor2  = (int*)alloc((size_t)NB * 4);
    int* hcnt      = (int*)alloc(4);
    uint* pair_buf = (uint*)alloc((size_t)N_EDGES * 4);
    ushort* csr    = (ushort*)alloc((size_t)N_EDGES * 2);
    float* pooled  = (float*)alloc(HIDDEN * 4);
    ushort* Wt1    = (ushort*)alloc((size_t)HIDDEN * NODE_DIM * 2);   // 64 KB
    ushort* Wt2    = (ushort*)alloc((size_t)HIDDEN * HIDDEN * 2);     // 128 KB
    uchar* nf_fp8  = (uchar*)alloc((size_t)N_NODES * NODE_DIM);       // 6.4 MB
    uchar* x1_fp8  = (uchar*)alloc((size_t)N_NODES * HIDDEN);         // 12.8 MB
    // +64 rows pad: gemm A-frag reads past row 49999 (results masked)
    ushort* agg1   = (ushort*)alloc((size_t)(N_NODES + 64) * NODE_DIM * 2);  // 12.8 MB
    ushort* agg2   = (ushort*)alloc((size_t)(N_NODES + 64) * HIDDEN * 2);    // 25.6 MB

    prep_kernel<<<(PREP6 + 255) / 256, 256, 0, stream>>>(
        node_features, W1, W2, nf_fp8, Wt1, Wt2, pooled, bcount, bcursor2, hcnt);

    bcount_kernel<<<P1_GRID, 256, 0, stream>>>(dst, bcount);
    bwrite_kernel<<<P1_GRID, 256, 0, stream>>>(src, dst, bcount, bcursor2, pair_buf);
    csrloc_kernel<<<NB, 256, 0, stream>>>(pair_buf, bcount, offsets, csr);

    const int AGG_GRID = (N_NODES * 64 + 255) / 256;
    const int G1_BLK = 512;   // halves co-located: 256 % 8 == 0
    const int G2_BLK = 512;   // quarters co-located: 128 % 8 == 0

    agg_kernel<NODE_DIM><<<AGG_GRID, 256, 0, stream>>>(nf_fp8, offsets, csr, agg1);
    gemm1_kernel<<<G1_BLK, 256, 0, stream>>>(agg1, Wt1, b1, x1_fp8, G1_BLK);

    agg_kernel<HIDDEN><<<AGG_GRID, 256, 0, stream>>>(x1_fp8, offsets, csr, agg2);
    gemm2_kernel<<<G2_BLK, 256, 0, stream>>>(
        agg2, Wt2, b2, pooled, G2_BLK,
        conditions, Wfc, bfc, Wmean, bmean, Wlogvar, blogvar, out, hcnt);
}

// Round 21
// 140.931 us; speedup vs baseline: 1.1632x; 1.1632x over previous
//
#include <hip/hip_runtime.h>

#define N_NODES   50000
#define N_EDGES   800000
#define NODE_DIM  128
#define HIDDEN    256
#define LATENT    128
#define COND      5

#define NB        196                          // buckets: dst>>8 (256-node ranges)
#define P1_CHUNK  4096
#define P1_GRID   ((N_EDGES + P1_CHUNK - 1) / P1_CHUNK)  // 196

typedef unsigned int uint;
typedef unsigned short ushort;
typedef unsigned char uchar;

typedef __attribute__((ext_vector_type(8))) short bf16x8;
typedef __attribute__((ext_vector_type(4))) float f32x4;

static __device__ __forceinline__ ushort f32_to_bf16(float f) {
    union { float f; uint u; } v; v.f = f;
    uint r = v.u + 0x7FFF + ((v.u >> 16) & 1);   // RNE
    return (ushort)(r >> 16);
}
static __device__ __forceinline__ uint pack_bf16(float lo, float hi) {
    return (uint)f32_to_bf16(lo) | ((uint)f32_to_bf16(hi) << 16);
}

// async global->LDS DMA, 16B per lane; LDS dest = wave-uniform base + lane*16
static __device__ __forceinline__ void gload_lds16(const void* g, void* l) {
    __builtin_amdgcn_global_load_lds(
        (const __attribute__((address_space(1))) unsigned int*)(unsigned long long)(uintptr_t)g,
        (__attribute__((address_space(3))) unsigned int*)(unsigned int)(uintptr_t)l,
        16, 0, 0);
}

// ---------------- fp8 e4m3 helpers (HW cvt with software fallback) ----------------

#if __has_builtin(__builtin_amdgcn_cvt_pk_f32_fp8) && __has_builtin(__builtin_amdgcn_cvt_pk_fp8_f32)
#define HW_FP8 1
#endif

#ifndef HW_FP8
static __device__ __forceinline__ float dec1_fp8(uint b) {
    uint sgn = b & 0x80, mag = b & 0x7f;
    float v;
    if (mag >= 8) {
        union { uint u; float f; } t;
        t.u = (((mag >> 3) + 120) << 23) | ((mag & 7) << 20);
        v = t.f;
    } else {
        v = (float)mag * 0.001953125f;   // 2^-9
    }
    return sgn ? -v : v;
}
static __device__ __forceinline__ uchar enc1_fp8(float f) {
    float a = fabsf(f);
    uint s = (f < 0.f) ? 0x80u : 0u;
    if (!(a >= 0.015625f)) {
        int q = (int)(a * 512.f + 0.5f);
        if (q > 7) q = 7;
        return (uchar)(s | (uint)q);
    }
    if (a >= 448.f) return (uchar)(s | 0x7E);
    union { float f; uint u; } t; t.f = a;
    uint e = (t.u >> 23) - 120;
    uint m = (t.u >> 20) & 7;
    uint rem = t.u & 0xFFFFF;
    uint v = (e << 3) | m;
    if (rem > 0x80000 || (rem == 0x80000 && (v & 1))) v++;
    if (v > 0x7E) v = 0x7E;
    return (uchar)(s | v);
}
#endif

static __device__ __forceinline__ void dec4_add(uint u, float* acc) {
#ifdef HW_FP8
    auto lo = __builtin_amdgcn_cvt_pk_f32_fp8((int)u, false);
    auto hi = __builtin_amdgcn_cvt_pk_f32_fp8((int)u, true);
    acc[0] += lo[0]; acc[1] += lo[1]; acc[2] += hi[0]; acc[3] += hi[1];
#else
    acc[0] += dec1_fp8(u & 0xff);
    acc[1] += dec1_fp8((u >> 8) & 0xff);
    acc[2] += dec1_fp8((u >> 16) & 0xff);
    acc[3] += dec1_fp8(u >> 24);
#endif
}
static __device__ __forceinline__ void dec2_add(uint u, float* acc) {
#ifdef HW_FP8
    auto lo = __builtin_amdgcn_cvt_pk_f32_fp8((int)u, false);
    acc[0] += lo[0]; acc[1] += lo[1];
#else
    acc[0] += dec1_fp8(u & 0xff);
    acc[1] += dec1_fp8((u >> 8) & 0xff);
#endif
}
static __device__ __forceinline__ uint enc2_fp8(float a, float b) {
#ifdef HW_FP8
    return (uint)__builtin_amdgcn_cvt_pk_fp8_f32(a, b, 0, false) & 0xFFFFu;
#else
    return (uint)enc1_fp8(a) | ((uint)enc1_fp8(b) << 8);
#endif
}
static __device__ __forceinline__ uchar enc1(float v) {
#ifdef HW_FP8
    return (uchar)(__builtin_amdgcn_cvt_pk_fp8_f32(v, v, 0, false) & 0xff);
#else
    return enc1_fp8(v);
#endif
}

// ---------------- prep: nf -> fp8, W -> DMA-packed bf16, zero scratch ----------------
// Wst layout (ushort): [kstep][chunk w=kg*4+cc][col' 0..63][k' 0..7]
//   idx = (((k>>5)*16) + (((k&31)>>3)*4 + (c>>6)))*64*8 + (c&63)*8 + (k&7)

#define NF4   (N_NODES * NODE_DIM / 4)            // 1,600,000
#define PREP1 (NF4 + NODE_DIM * HIDDEN)           // + 32768  (W1)
#define PREP2 (PREP1 + HIDDEN * HIDDEN)           // + 65536  (W2)
#define PREP3 (PREP2 + HIDDEN)                    // + 256    (pooled zero)
#define PREP4 (PREP3 + NB)                        // + 196    (bcount zero)
#define PREP5 (PREP4 + NB)                        // + 196    (bcursor2 zero)
#define PREP6 (PREP5 + 1)                         // + 1      (hcnt zero)

__global__ void prep_kernel(const float* __restrict__ nf,
                            const float* __restrict__ W1, const float* __restrict__ W2,
                            uchar* __restrict__ nf_fp8,
                            ushort* __restrict__ Wst1, ushort* __restrict__ Wst2,
                            float* __restrict__ pooled,
                            int* __restrict__ bcount, int* __restrict__ bcursor2,
                            int* __restrict__ hcnt) {
    int id = blockIdx.x * blockDim.x + threadIdx.x;
    if (id < NF4) {
        float4 v = reinterpret_cast<const float4*>(nf)[id];
        uint w = enc2_fp8(v.x, v.y) | (enc2_fp8(v.z, v.w) << 16);
        reinterpret_cast<uint*>(nf_fp8)[id] = w;
    } else if (id < PREP1) {
        int i = id - NF4;
        int k = i >> 8, c = i & 255;
        int idx = ((((k >> 5) * 16) + (((k & 31) >> 3) * 4 + (c >> 6))) * 64 + (c & 63)) * 8 + (k & 7);
        Wst1[idx] = f32_to_bf16(W1[i]);
    } else if (id < PREP2) {
        int i = id - PREP1;
        int k = i >> 8, c = i & 255;
        int idx = ((((k >> 5) * 16) + (((k & 31) >> 3) * 4 + (c >> 6))) * 64 + (c & 63)) * 8 + (k & 7);
        Wst2[idx] = f32_to_bf16(W2[i]);
    } else if (id < PREP3) {
        pooled[id - PREP2] = 0.f;
    } else if (id < PREP4) {
        bcount[id - PREP3] = 0;
    } else if (id < PREP5) {
        bcursor2[id - PREP4] = 0;
    } else if (id < PREP6) {
        hcnt[0] = 0;
    }
}

// ---------------- CSR build: bucket count -> pair write -> per-bucket local CSR ----------------

__global__ __launch_bounds__(256) void bcount_kernel(const int* __restrict__ dst,
                                                     int* __restrict__ bcount) {
    __shared__ int cnt[NB];
    const int t = threadIdx.x;
    for (int i = t; i < NB; i += 256) cnt[i] = 0;
    __syncthreads();
    const int base = blockIdx.x * P1_CHUNK;
#pragma unroll
    for (int i = 0; i < 16; ++i) {
        int e = base + i * 256 + t;
        if (e < N_EDGES) atomicAdd(&cnt[dst[e] >> 8], 1);
    }
    __syncthreads();
    for (int i = t; i < NB; i += 256)
        if (cnt[i] > 0) atomicAdd(&bcount[i], cnt[i]);
}

__global__ __launch_bounds__(256) void bwrite_kernel(const int* __restrict__ src,
                                                     const int* __restrict__ dst,
                                                     const int* __restrict__ bcount,
                                                     int* __restrict__ bcursor2,
                                                     uint* __restrict__ pair_buf) {
    __shared__ int s[256];
    __shared__ int cnt[NB];
    __shared__ int gbase[NB];
    const int t = threadIdx.x;
    s[t] = (t < NB) ? bcount[t] : 0;
    __syncthreads();
    for (int off = 1; off < 256; off <<= 1) {
        int v = (t >= off) ? s[t - off] : 0;
        __syncthreads();
        s[t] += v;
        __syncthreads();
    }
    for (int i = t; i < NB; i += 256) cnt[i] = 0;
    __syncthreads();

    const int base = blockIdx.x * P1_CHUNK;
    uint pk[16];
    int  bk[16], lr[16];
    bool ok[16];
#pragma unroll
    for (int i = 0; i < 16; ++i) {
        int e = base + i * 256 + t;
        ok[i] = e < N_EDGES;
        if (ok[i]) {
            int sv = src[e], d = dst[e];
            pk[i] = (uint)sv | ((uint)d << 16);
            bk[i] = d >> 8;
        }
    }
#pragma unroll
    for (int i = 0; i < 16; ++i)
        if (ok[i]) lr[i] = atomicAdd(&cnt[bk[i]], 1);
    __syncthreads();
    if (t < NB) {
        int c = cnt[t];
        if (c > 0) gbase[t] = ((t > 0) ? s[t - 1] : 0) + atomicAdd(&bcursor2[t], c);
    }
    __syncthreads();
#pragma unroll
    for (int i = 0; i < 16; ++i)
        if (ok[i]) pair_buf[gbase[bk[i]] + lr[i]] = pk[i];
}

__global__ __launch_bounds__(256) void csrloc_kernel(const uint* __restrict__ pair_buf,
                                                     const int* __restrict__ bcount,
                                                     int* __restrict__ offsets,
                                                     ushort* __restrict__ csr) {
    __shared__ int s[256];
    __shared__ int lcnt[256];
    __shared__ int loff[256];
    __shared__ int lcur[256];
    const int t = threadIdx.x;
    const int b = blockIdx.x;
    s[t] = (t < NB) ? bcount[t] : 0;
    __syncthreads();
    for (int off = 1; off < 256; off <<= 1) {
        int v = (t >= off) ? s[t - off] : 0;
        __syncthreads();
        s[t] += v;
        __syncthreads();
    }
    const int e0 = (b > 0) ? s[b - 1] : 0;
    const int e1 = s[b];
    lcnt[t] = 0;
    lcur[t] = 0;
    __syncthreads();

    for (int j = e0 + t; j < e1; j += 256)
        atomicAdd(&lcnt[(pair_buf[j] >> 16) & 255], 1);
    __syncthreads();

    const int myc = lcnt[t];
    s[t] = myc;
    __syncthreads();
    for (int off = 1; off < 256; off <<= 1) {
        int v = (t >= off) ? s[t - off] : 0;
        __syncthreads();
        s[t] += v;
        __syncthreads();
    }
    const int lofft = s[t] - myc;   // exclusive
    loff[t] = lofft;
    const int node = (b << 8) + t;
    if (node < N_NODES) offsets[node] = e0 + lofft;
    if (b == 0 && t == 0) offsets[N_NODES] = N_EDGES;
    __syncthreads();

    for (int j = e0 + t; j < e1; j += 256) {
        uint p = pair_buf[j];
        int dl = (int)(p >> 16) & 255;
        int r = atomicAdd(&lcur[dl], 1);
        csr[e0 + loff[dl] + r] = (ushort)(p & 0xFFFFu);
    }
}

// ---------------- aggregation: wave per node, fp8 gather, bf16 out, 16-deep pipeline ----------------

template <int D>
__global__ __launch_bounds__(256) void agg_kernel(const uchar* __restrict__ x,
                                                  const int* __restrict__ offsets,
                                                  const ushort* __restrict__ csr,
                                                  ushort* __restrict__ out) {
    constexpr int BPL = D / 64;   // bytes per lane: 2 or 4
    int node = (blockIdx.x * blockDim.x + threadIdx.x) >> 6;
    int lane = threadIdx.x & 63;
    if (node >= N_NODES) return;
    int j0 = __builtin_amdgcn_readfirstlane(offsets[node]);
    int j1 = __builtin_amdgcn_readfirstlane(offsets[node + 1]);

    float acc[BPL];
#pragma unroll
    for (int i = 0; i < BPL; ++i) acc[i] = 0.f;

    const uchar* base = x + lane * BPL;
    const int il = lane & 15;

    int idxv = (j0 + il < j1) ? (int)csr[j0 + il] : 0;

    for (int jb = j0; jb < j1; jb += 16) {
        int idxn = (jb + 16 + il < j1) ? (int)csr[jb + 16 + il] : 0;
        int n = j1 - jb; n = (n > 16) ? 16 : n;
        uint u[16];
        if (n == 16) {
#pragma unroll
            for (int i = 0; i < 16; ++i) {
                int s = __shfl(idxv, i);
                if constexpr (BPL == 4)
                    u[i] = *reinterpret_cast<const uint*>(base + (size_t)s * D);
                else
                    u[i] = *reinterpret_cast<const ushort*>(base + (size_t)s * D);
            }
#pragma unroll
            for (int i = 0; i < 16; ++i) {
                if constexpr (BPL == 4) dec4_add(u[i], acc); else dec2_add(u[i], acc);
            }
        } else {
#pragma unroll
            for (int i = 0; i < 16; ++i) {
                if (i < n) {
                    int s = __shfl(idxv, i);
                    if constexpr (BPL == 4)
                        u[i] = *reinterpret_cast<const uint*>(base + (size_t)s * D);
                    else
                        u[i] = *reinterpret_cast<const ushort*>(base + (size_t)s * D);
                }
            }
#pragma unroll
            for (int i = 0; i < 16; ++i) {
                if (i < n) {
                    if constexpr (BPL == 4) dec4_add(u[i], acc); else dec2_add(u[i], acc);
                }
            }
        }
        idxv = idxn;
    }

    if constexpr (BPL == 4) {
        uint2 o;
        o.x = pack_bf16(acc[0], acc[1]);
        o.y = pack_bf16(acc[2], acc[3]);
        *reinterpret_cast<uint2*>(out + (size_t)node * D + lane * 4) = o;
    } else {
        *reinterpret_cast<uint*>(out + (size_t)node * D + lane * 2) = pack_bf16(acc[0], acc[1]);
    }
}

// ---------------- GEMM1 (K=128): persistent, W-half resident, XCD-co-located halves ----------------
// block = 64 rows x 128 cols; grid 512; colhalf = bid/256 (256 % 8 == 0 -> both halves
// of a row-tile on the SAME XCD, A tile fetched once per XCD). LDS 64KB -> 2 blocks/CU.

__global__ __launch_bounds__(256) void gemm1_kernel(const ushort* __restrict__ A,
                                                    const ushort* __restrict__ Wst,
                                                    const float* __restrict__ bias,
                                                    uchar* __restrict__ Xout, int nblk) {
    constexpr int K = NODE_DIM;
    constexpr int NSTEP = K / 32;              // 4
    constexpr int WB    = NSTEP * 8 * 1024;    // 32KB
    constexpr int AB    = NSTEP * 4 * 1024;    // 16KB
    constexpr int NT    = (N_NODES + 63) / 64; // 782
    __shared__ uchar lds[WB + 2 * AB];

    const int t    = threadIdx.x;
    const int lane = t & 63;
    const int wv   = t >> 6;
    const int fr   = lane & 15;
    const int kgl  = lane >> 4;
    const int half    = nblk >> 1;             // 256 (mod 8 == 0 -> co-located)
    const int colhalf = blockIdx.x / half;
    const int stride  = half;

    const int kx = (lane & 3) ^ ((lane >> 3) & 3);   // A source k-group swizzle

#pragma unroll
    for (int j = 0; j < NSTEP * 2; ++j) {
        const int lc = wv * (NSTEP * 2) + j;
        const int ks = lc >> 3, r = lc & 7;
        const int kg = r >> 1, ccl = r & 1;
        gload_lds16(Wst + ((size_t)ks * 16 + kg * 4 + colhalf * 2 + ccl) * 512 + lane * 8,
                    &lds[lc * 1024]);
    }

    auto stageA = [&](int buf, int row0) {
#pragma unroll
        for (int j = 0; j < NSTEP; ++j) {
            const int c  = wv * NSTEP + j;
            const int ks = c >> 2, rt = c & 3;
            gload_lds16(A + (size_t)(row0 + rt * 16 + (lane >> 2)) * K + ks * 32 + kx * 8,
                        &lds[WB + buf * AB + c * 1024]);
        }
    };

    const int rowsel = (wv & 1) * 2;
    const int colsel = wv >> 1;
    const int col0   = colhalf * 128 + colsel * 64;
    float bcol[4];
#pragma unroll
    for (int ct = 0; ct < 4; ++ct) bcol[ct] = bias[col0 + ct * 16 + fr];
    const int mrow = kgl * 4;
    const int aswz = (kgl ^ ((fr >> 1) & 3)) * 16;

    int tile = blockIdx.x % half;
    stageA(0, tile * 64);
    __syncthreads();

    for (int buf = 0; tile < NT; tile += stride, buf ^= 1) {
        const int tn = tile + stride;
        if (tn < NT) stageA(buf ^ 1, tn * 64);

        f32x4 acc[2][4];
#pragma unroll
        for (int rt = 0; rt < 2; ++rt)
#pragma unroll
            for (int ct = 0; ct < 4; ++ct)
                acc[rt][ct] = (f32x4){0.f, 0.f, 0.f, 0.f};

        const uchar* ab = &lds[WB + buf * AB];
#pragma unroll
        for (int ks = 0; ks < NSTEP; ++ks) {
            bf16x8 af[2], bfv[4];
#pragma unroll
            for (int rt = 0; rt < 2; ++rt)
                af[rt] = *reinterpret_cast<const bf16x8*>(ab + (ks * 4 + rowsel + rt) * 1024 + fr * 64 + aswz);
#pragma unroll
            for (int ct = 0; ct < 4; ++ct)
                bfv[ct] = *reinterpret_cast<const bf16x8*>(&lds[(ks * 8 + kgl * 2 + colsel) * 1024 + (ct * 16 + fr) * 16]);
#pragma unroll
            for (int rt = 0; rt < 2; ++rt)
#pragma unroll
                for (int ct = 0; ct < 4; ++ct)
                    acc[rt][ct] = __builtin_amdgcn_mfma_f32_16x16x32_bf16(af[rt], bfv[ct], acc[rt][ct], 0, 0, 0);
        }

        const int rowbase = tile * 64 + (wv & 1) * 32;
#pragma unroll
        for (int rt = 0; rt < 2; ++rt) {
#pragma unroll
            for (int e = 0; e < 4; ++e) {
                int m = rowbase + rt * 16 + mrow + e;
                if (m < N_NODES) {
#pragma unroll
                    for (int ct = 0; ct < 4; ++ct) {
                        float v = fmaxf(acc[rt][ct][e] + bcol[ct], 0.f);
                        Xout[(size_t)m * HIDDEN + col0 + ct * 16 + fr] = enc1(v);
                    }
                }
            }
        }
        __syncthreads();
    }
}

// ---------------- GEMM2 (K=256): col-quarter W resident, XCD-co-located quarters ----------------
// block = 32 rows x 64 cols; grid 512; colq = bid/128 (128 % 8 == 0 -> all 4 quarters
// of a row-tile on the SAME XCD -> A tile fetched once). LDS 64KB -> 2 blocks/CU.

__global__ __launch_bounds__(256) void gemm2_kernel(const ushort* __restrict__ A,
                                                    const ushort* __restrict__ Wst,
                                                    const float* __restrict__ bias,
                                                    float* __restrict__ pooled, int nblk,
                                                    const float* __restrict__ cond,
                                                    const float* __restrict__ Wfc,
                                                    const float* __restrict__ bfc,
                                                    const float* __restrict__ Wmean,
                                                    const float* __restrict__ bmean,
                                                    const float* __restrict__ Wlogvar,
                                                    const float* __restrict__ blogvar,
                                                    float* __restrict__ outv,
                                                    int* __restrict__ hcnt) {
    constexpr int K   = HIDDEN;                 // 256
    constexpr int WB  = 32768;                  // 64 cols x 256 k x 2B
    constexpr int AB  = 16384;                  // 32 rows x 256 k x 2B
    constexpr int NT  = (N_NODES + 31) / 32;    // 1563
    __shared__ uchar lds[WB + 2 * AB];
    __shared__ int lastflag;

    const int t    = threadIdx.x;
    const int lane = t & 63;
    const int wv   = t >> 6;
    const int fr   = lane & 15;
    const int kgl  = lane >> 4;
    const int q      = nblk >> 2;               // 128 (mod 8 == 0 -> co-located)
    const int colq   = blockIdx.x / q;
    const int stride = q;

    const int kx = (lane & 3) ^ ((lane >> 3) & 3);   // A source k-group swizzle

    // ---- W quarter load (once): 32 chunks of 1KB ----
#pragma unroll
    for (int j = 0; j < 8; ++j) {
        const int lc = wv * 8 + j;              // 0..31, wave-uniform
        const int ks = lc >> 2, kg = lc & 3;
        gload_lds16(Wst + ((size_t)ks * 16 + kg * 4 + colq) * 512 + lane * 8,
                    &lds[lc * 1024]);
    }

    auto stageA = [&](int buf, int row0) {
#pragma unroll
        for (int j = 0; j < 4; ++j) {
            const int c  = wv * 4 + j;          // 0..15, wave-uniform
            const int ks = c >> 1, rh = c & 1;
            gload_lds16(A + (size_t)(row0 + rh * 16 + (lane >> 2)) * K + ks * 32 + kx * 8,
                        &lds[WB + buf * AB + c * 1024]);
        }
    };

    const int rowhalf = wv & 1;                 // 16-row half of the 32-row tile
    const int colh32  = wv >> 1;                // 32-col half of the 64-col quarter
    const int col0    = colq * 64 + colh32 * 32;
    float bcol[2];
#pragma unroll
    for (int ct = 0; ct < 2; ++ct) bcol[ct] = bias[col0 + ct * 16 + fr];
    const int mrow = kgl * 4;
    const int aswz = (kgl ^ ((fr >> 1) & 3)) * 16;

    float cs[2] = {0.f, 0.f};
    int tile = blockIdx.x % q;
    stageA(0, tile * 32);
    __syncthreads();                            // drains W + first A

    for (int buf = 0; tile < NT; tile += stride, buf ^= 1) {
        const int tn = tile + stride;
        if (tn < NT) stageA(buf ^ 1, tn * 32);

        f32x4 acc[2];
        acc[0] = (f32x4){0.f, 0.f, 0.f, 0.f};
        acc[1] = (f32x4){0.f, 0.f, 0.f, 0.f};

        const uchar* ab = &lds[WB + buf * AB];
#pragma unroll
        for (int ks = 0; ks < 8; ++ks) {
            bf16x8 af, bfv[2];
            af = *reinterpret_cast<const bf16x8*>(ab + (ks * 2 + rowhalf) * 1024 + fr * 64 + aswz);
#pragma unroll
            for (int ct = 0; ct < 2; ++ct)
                bfv[ct] = *reinterpret_cast<const bf16x8*>(
                    &lds[(ks * 4 + kgl) * 1024 + (colh32 * 32 + ct * 16 + fr) * 16]);
#pragma unroll
            for (int ct = 0; ct < 2; ++ct)
                acc[ct] = __builtin_amdgcn_mfma_f32_16x16x32_bf16(af, bfv[ct], acc[ct], 0, 0, 0);
        }

        const int rowbase = tile * 32 + rowhalf * 16;
#pragma unroll
        for (int e = 0; e < 4; ++e) {
            int m = rowbase + mrow + e;
            if (m < N_NODES) {
                cs[0] += fmaxf(acc[0][e] + bcol[0], 0.f);
                cs[1] += fmaxf(acc[1][e] + bcol[1], 0.f);
            }
        }
        __syncthreads();   // readers done with buf; next-tile DMAs drained (covered by compute)
    }

#pragma unroll
    for (int ct = 0; ct < 2; ++ct) {
        cs[ct] += __shfl_xor(cs[ct], 16);
        cs[ct] += __shfl_xor(cs[ct], 32);
    }
    if (lane < 16) {
#pragma unroll
        for (int ct = 0; ct < 2; ++ct)
            atomicAdd(&pooled[col0 + ct * 16 + lane], cs[ct]);
    }

    // ---- fused head: last block runs the MLP ----
    asm volatile("s_waitcnt vmcnt(0)" ::: "memory");
    __syncthreads();
    if (t == 0) lastflag = (atomicAdd(hcnt, 1) == nblk - 1) ? 1 : 0;
    __syncthreads();
    if (lastflag) {
        float* hv = (float*)lds;               // LDS reuse (GEMM work done)
        float* hh = (float*)(lds + 2048);
        if (t < HIDDEN) hv[t] = atomicAdd(&pooled[t], 0.0f) * (1.0f / N_NODES);
        if (t < COND) hv[HIDDEN + t] = cond[t];
        __syncthreads();
        if (t < LATENT) {
            float s = bfc[t];
            for (int k = 0; k < HIDDEN + COND; ++k) s += hv[k] * Wfc[k * LATENT + t];
            hh[t] = fmaxf(s, 0.f);
        }
        __syncthreads();
        if (t < LATENT) {
            float s = bmean[t];
            for (int k = 0; k < LATENT; ++k) s += hh[k] * Wmean[k * LATENT + t];
            outv[t] = s;
        } else if (t < 2 * LATENT) {
            int j = t - LATENT;
            float s = blogvar[j];
            for (int k = 0; k < LATENT; ++k) s += hh[k] * Wlogvar[k * LATENT + j];
            outv[LATENT + j] = s;
        }
    }
}

// ---------------- launch ----------------

extern "C" void kernel_launch(void* const* d_in, const int* in_sizes, int n_in,
                              void* d_out, int out_size, void* d_ws, size_t ws_size,
                              hipStream_t stream) {
    const float* node_features = (const float*)d_in[0];
    const float* conditions    = (const float*)d_in[1];
    const int*   src           = (const int*)d_in[2];
    const int*   dst           = (const int*)d_in[3];
    const float* W1  = (const float*)d_in[4];
    const float* b1  = (const float*)d_in[5];
    const float* W2  = (const float*)d_in[6];
    const float* b2  = (const float*)d_in[7];
    const float* Wfc = (const float*)d_in[8];
    const float* bfc = (const float*)d_in[9];
    const float* Wmean   = (const float*)d_in[10];
    const float* bmean   = (const float*)d_in[11];
    const float* Wlogvar = (const float*)d_in[12];
    const float* blogvar = (const float*)d_in[13];
    float* out = (float*)d_out;

    size_t o = 0;
    auto alloc = [&](size_t bytes) {
        void* p = (char*)d_ws + o;
        o += (bytes + 255) & ~(size_t)255;
        return p;
    };
    int* offsets   = (int*)alloc((size_t)(N_NODES + 1) * 4);
    int* bcount    = (int*)alloc((size_t)NB * 4);
    int* bcursor2  = (int*)alloc((size_t)NB * 4);
    int* hcnt      = (int*)alloc(4);
    uint* pair_buf = (uint*)alloc((size_t)N_EDGES * 4);
    ushort* csr    = (ushort*)alloc((size_t)N_EDGES * 2);
    float* pooled  = (float*)alloc(HIDDEN * 4);
    ushort* Wst1   = (ushort*)alloc((size_t)HIDDEN * NODE_DIM * 2);   // 64 KB
    ushort* Wst2   = (ushort*)alloc((size_t)HIDDEN * HIDDEN * 2);     // 128 KB
    uchar* nf_fp8  = (uchar*)alloc((size_t)N_NODES * NODE_DIM);       // 6.4 MB
    uchar* x1_fp8  = (uchar*)alloc((size_t)N_NODES * HIDDEN);         // 12.8 MB
    // +64 rows pad: gemm staging reads past row 49999 (results masked)
    ushort* agg1   = (ushort*)alloc((size_t)(N_NODES + 64) * NODE_DIM * 2);  // 12.8 MB
    ushort* agg2   = (ushort*)alloc((size_t)(N_NODES + 64) * HIDDEN * 2);    // 25.6 MB

    prep_kernel<<<(PREP6 + 255) / 256, 256, 0, stream>>>(
        node_features, W1, W2, nf_fp8, Wst1, Wst2, pooled, bcount, bcursor2, hcnt);

    bcount_kernel<<<P1_GRID, 256, 0, stream>>>(dst, bcount);
    bwrite_kernel<<<P1_GRID, 256, 0, stream>>>(src, dst, bcount, bcursor2, pair_buf);
    csrloc_kernel<<<NB, 256, 0, stream>>>(pair_buf, bcount, offsets, csr);

    const int AGG_GRID = (N_NODES * 64 + 255) / 256;
    const int G1_BLK = 512;   // halves co-located: 256 % 8 == 0
    const int G2_BLK = 512;   // quarters co-located: 128 % 8 == 0

    agg_kernel<NODE_DIM><<<AGG_GRID, 256, 0, stream>>>(nf_fp8, offsets, csr, agg1);
    gemm1_kernel<<<G1_BLK, 256, 0, stream>>>(agg1, Wst1, b1, x1_fp8, G1_BLK);

    agg_kernel<HIDDEN><<<AGG_GRID, 256, 0, stream>>>(x1_fp8, offsets, csr, agg2);
    gemm2_kernel<<<G2_BLK, 256, 0, stream>>>(
        agg2, Wst2, b2, pooled, G2_BLK,
        conditions, Wfc, bfc, Wmean, bmean, Wlogvar, blogvar, out, hcnt);
}